// Round 1
// baseline (906.998 us; speedup 1.0000x reference)
//
#include <hip/hip_runtime.h>

#define IN_C 128
#define HEADS 4
#define OUT_C 64
#define OUT_F 256   // HEADS*OUT_C
#define NEG_SLOPE 0.2f
#define BN_EPS 1e-5f

// ---------------- GEMM: h = x @ W, plus per-head attention dots ----------------
// Block = 256 threads (thread t owns output column t), 8 nodes per block.
__global__ __launch_bounds__(256) void gemm_kernel(
    const float* __restrict__ x, const float* __restrict__ W,
    const float* __restrict__ att_src, const float* __restrict__ att_dst,
    float* __restrict__ h, float* __restrict__ a_src, float* __restrict__ a_dst,
    int n)
{
    __shared__ float xs[8 * IN_C];   // 4 KB
    const int t = threadIdx.x;
    const int base = blockIdx.x * 8;

    // stage 8 rows of x (1024 floats) cooperatively, coalesced float4
    if (base + 8 <= n) {
        const float4* src = (const float4*)(x + (size_t)base * IN_C);
        ((float4*)xs)[t] = src[t];
    } else {
        // tail guard (not hit for n=100000)
        for (int i = t; i < 8 * IN_C; i += 256) {
            int node = base + i / IN_C;
            xs[i] = (node < n) ? x[(size_t)node * IN_C + (i % IN_C)] : 0.f;
        }
    }
    __syncthreads();

    const float as_w = att_src[t];
    const float ad_w = att_dst[t];

    float acc[8];
#pragma unroll
    for (int m = 0; m < 8; ++m) acc[m] = 0.f;

    for (int k = 0; k < IN_C; k += 4) {
        float w0 = W[(size_t)(k + 0) * OUT_F + t];
        float w1 = W[(size_t)(k + 1) * OUT_F + t];
        float w2 = W[(size_t)(k + 2) * OUT_F + t];
        float w3 = W[(size_t)(k + 3) * OUT_F + t];
#pragma unroll
        for (int m = 0; m < 8; ++m) {
            float4 xv = *(const float4*)&xs[m * IN_C + k];
            acc[m] = fmaf(xv.x, w0, acc[m]);
            acc[m] = fmaf(xv.y, w1, acc[m]);
            acc[m] = fmaf(xv.z, w2, acc[m]);
            acc[m] = fmaf(xv.w, w3, acc[m]);
        }
    }

    const int head = t >> 6;
    const int lane = t & 63;
#pragma unroll
    for (int m = 0; m < 8; ++m) {
        int node = base + m;
        if (node >= n) break;
        h[(size_t)node * OUT_F + t] = acc[m];
        float vs = acc[m] * as_w;
        float vd = acc[m] * ad_w;
#pragma unroll
        for (int o = 32; o > 0; o >>= 1) {
            vs += __shfl_down(vs, o, 64);
            vd += __shfl_down(vd, o, 64);
        }
        if (lane == 0) {
            a_src[(size_t)node * HEADS + head] = vs;
            a_dst[(size_t)node * HEADS + head] = vd;
        }
    }
}

// ---------------- CSR build ----------------
__global__ void deg_kernel(const int* __restrict__ ei, int* __restrict__ deg, int E)
{
    int e = blockIdx.x * blockDim.x + threadIdx.x;
    if (e < E) atomicAdd(&deg[ei[E + e]], 1);
}

__global__ void offsets_kernel(const int* __restrict__ deg, int* __restrict__ offsets,
                               int* __restrict__ cursor, int* __restrict__ gcursor, int n)
{
    int i = blockIdx.x * blockDim.x + threadIdx.x;
    int lane = threadIdx.x & 63;
    int cnt = (i < n) ? deg[i] : 0;
    int incl = cnt;
#pragma unroll
    for (int o = 1; o < 64; o <<= 1) {
        int v = __shfl_up(incl, o, 64);
        if (lane >= o) incl += v;
    }
    int total = __shfl(incl, 63, 64);
    int base = 0;
    if (lane == 63) base = atomicAdd(gcursor, total);
    base = __shfl(base, 63, 64);
    int off = base + incl - cnt;
    if (i < n) { offsets[i] = off; cursor[i] = off; }
}

__global__ void scatter_kernel(const int* __restrict__ ei, int* __restrict__ cursor,
                               int* __restrict__ srcs, int E)
{
    int e = blockIdx.x * blockDim.x + threadIdx.x;
    if (e < E) {
        int dst = ei[E + e];
        int pos = atomicAdd(&cursor[dst], 1);
        srcs[pos] = ei[e];
    }
}

// ---------------- Aggregation: one wave per destination node ----------------
__device__ __forceinline__ float pick_head(float4 v, int h) {
    float lo = (h == 0) ? v.x : v.y;
    float hi = (h == 2) ? v.z : v.w;
    return (h < 2) ? lo : hi;
}

__global__ __launch_bounds__(256) void agg_kernel(
    const float* __restrict__ h, const float* __restrict__ a_src,
    const float* __restrict__ a_dst, const int* __restrict__ offsets,
    const int* __restrict__ deg, const int* __restrict__ srcs,
    const float* __restrict__ bias, float* __restrict__ out, int n)
{
    int wave = (blockIdx.x * blockDim.x + threadIdx.x) >> 6;
    int lane = threadIdx.x & 63;
    int dst = wave;
    if (dst >= n) return;
    int myh = lane >> 4;   // float4 index `lane` covers channels lane*4..lane*4+3, all in head lane>>4

    float4 ad4 = ((const float4*)a_dst)[dst];
    float adh = pick_head(ad4, myh);

    // self loop
    float4 as4 = ((const float4*)a_src)[dst];
    float es = pick_head(as4, myh) + adh;
    es = (es > 0.f) ? es : NEG_SLOPE * es;
    float w = expf(es);
    float4 hv = ((const float4*)(h + (size_t)dst * OUT_F))[lane];
    float4 acc;
    acc.x = hv.x * w; acc.y = hv.y * w; acc.z = hv.z * w; acc.w = hv.w * w;
    float wsum = w;

    int start = offsets[dst];
    int cnt = deg[dst];
    for (int j = 0; j < cnt; ++j) {
        int s = srcs[start + j];
        float4 as = ((const float4*)a_src)[s];
        float e = pick_head(as, myh) + adh;
        e = (e > 0.f) ? e : NEG_SLOPE * e;
        float we = expf(e);
        float4 hs = ((const float4*)(h + (size_t)s * OUT_F))[lane];
        acc.x = fmaf(hs.x, we, acc.x);
        acc.y = fmaf(hs.y, we, acc.y);
        acc.z = fmaf(hs.z, we, acc.z);
        acc.w = fmaf(hs.w, we, acc.w);
        wsum += we;
    }

    float inv = 1.f / (wsum + 1e-16f);
    float4 b4 = ((const float4*)bias)[lane];
    float4 o4;
    o4.x = acc.x * inv + b4.x;
    o4.y = acc.y * inv + b4.y;
    o4.z = acc.z * inv + b4.z;
    o4.w = acc.w * inv + b4.w;
    ((float4*)(out + (size_t)dst * OUT_F))[lane] = o4;
}

// ---------------- BatchNorm stats + apply + ELU ----------------
__global__ __launch_bounds__(256) void stats_kernel(const float* __restrict__ out,
                                                    float* __restrict__ stats, int n)
{
    int c = threadIdx.x;
    float s = 0.f, s2 = 0.f;
    for (int r = blockIdx.x; r < n; r += gridDim.x) {
        float v = out[(size_t)r * OUT_F + c];
        s += v;
        s2 = fmaf(v, v, s2);
    }
    atomicAdd(&stats[c], s);
    atomicAdd(&stats[OUT_F + c], s2);
}

__global__ void scaleshift_kernel(const float* __restrict__ stats,
                                  const float* __restrict__ gamma,
                                  const float* __restrict__ beta,
                                  float* __restrict__ ss, int n)
{
    int c = threadIdx.x;
    float invn = 1.f / (float)n;
    float mean = stats[c] * invn;
    float var = stats[OUT_F + c] * invn - mean * mean;
    float sc = gamma[c] * rsqrtf(var + BN_EPS);
    ss[c] = sc;
    ss[OUT_F + c] = beta[c] - mean * sc;
}

__device__ __forceinline__ float elu1(float v) {
    return (v > 0.f) ? v : expm1f(v);
}

__global__ __launch_bounds__(256) void bn_elu_kernel(float* __restrict__ out,
                                                     const float* __restrict__ ss,
                                                     long long n4)
{
    long long idx = (long long)blockIdx.x * blockDim.x + threadIdx.x;
    if (idx >= n4) return;
    int col4 = (int)(idx & 63);
    float4 v = ((float4*)out)[idx];
    float4 sc = ((const float4*)ss)[col4];
    float4 sh = ((const float4*)(ss + OUT_F))[col4];
    v.x = elu1(fmaf(v.x, sc.x, sh.x));
    v.y = elu1(fmaf(v.y, sc.y, sh.y));
    v.z = elu1(fmaf(v.z, sc.z, sh.z));
    v.w = elu1(fmaf(v.w, sc.w, sh.w));
    ((float4*)out)[idx] = v;
}

// ---------------- launch ----------------
extern "C" void kernel_launch(void* const* d_in, const int* in_sizes, int n_in,
                              void* d_out, int out_size, void* d_ws, size_t ws_size,
                              hipStream_t stream)
{
    const float* x       = (const float*)d_in[0];
    const int*   ei      = (const int*)d_in[1];
    const float* W       = (const float*)d_in[2];
    const float* att_src = (const float*)d_in[3];
    const float* att_dst = (const float*)d_in[4];
    const float* bias    = (const float*)d_in[5];
    const float* gamma   = (const float*)d_in[6];
    const float* beta    = (const float*)d_in[7];
    float* out = (float*)d_out;

    const int n = in_sizes[0] / IN_C;      // 100000
    const int E = in_sizes[1] / 2;         // 1600000

    // ws layout (4-byte units)
    float* ws = (float*)d_ws;
    size_t o = 0;
    float* h      = ws + o; o += (size_t)n * OUT_F;   // 25.6M
    float* a_src  = ws + o; o += (size_t)n * HEADS;
    float* a_dst  = ws + o; o += (size_t)n * HEADS;
    float* ss     = ws + o; o += 2 * OUT_F;
    int* offsets  = (int*)(ws + o); o += n;
    int* cursor   = (int*)(ws + o); o += n;
    int* srcs     = (int*)(ws + o); o += E;
    // zero-initialized region (contiguous): deg, stats, gcursor
    int* deg      = (int*)(ws + o); o += n;
    float* stats  = ws + o; o += 2 * OUT_F;
    int* gcursor  = (int*)(ws + o); o += 1;

    hipMemsetAsync(deg, 0, ((size_t)n + 2 * OUT_F + 1) * sizeof(int), stream);

    gemm_kernel<<<(n + 7) / 8, 256, 0, stream>>>(x, W, att_src, att_dst, h, a_src, a_dst, n);
    deg_kernel<<<(E + 255) / 256, 256, 0, stream>>>(ei, deg, E);
    offsets_kernel<<<(n + 255) / 256, 256, 0, stream>>>(deg, offsets, cursor, gcursor, n);
    scatter_kernel<<<(E + 255) / 256, 256, 0, stream>>>(ei, cursor, srcs, E);
    agg_kernel<<<(n + 3) / 4, 256, 0, stream>>>(h, a_src, a_dst, offsets, deg, srcs, bias, out, n);
    stats_kernel<<<256, 256, 0, stream>>>(out, stats, n);
    scaleshift_kernel<<<1, 256, 0, stream>>>(stats, gamma, beta, ss, n);
    bn_elu_kernel<<<(int)(((long long)n * 64 + 255) / 256), 256, 0, stream>>>(out, ss, (long long)n * 64);
}

// Round 2
// 685.330 us; speedup vs baseline: 1.3234x; 1.3234x over previous
//
#include <hip/hip_runtime.h>

#define IN_C 128
#define HEADS 4
#define OUT_C 64
#define OUT_F 256   // HEADS*OUT_C
#define NEG_SLOPE 0.2f
#define BN_EPS 1e-5f
#define SP_BLOCKS 1024

typedef __attribute__((ext_vector_type(8))) short short8;
typedef __attribute__((ext_vector_type(4))) float floatx4;

__device__ __forceinline__ unsigned short f2bf(float f) {
    unsigned u = __float_as_uint(f);
    u += 0x7FFF + ((u >> 16) & 1);   // round-to-nearest-even
    return (unsigned short)(u >> 16);
}
__device__ __forceinline__ float bf2f(unsigned short u) {
    return __uint_as_float(((unsigned)u) << 16);
}

// ---------------- Wt prep: Wt[col][k] = bf16(W[k][col]) ----------------
__global__ void wtprep_kernel(const float* __restrict__ W, unsigned short* __restrict__ Wt)
{
    int i = blockIdx.x * blockDim.x + threadIdx.x;   // 0..32767
    int c = i >> 7, k = i & 127;
    Wt[i] = f2bf(W[(size_t)k * OUT_F + c]);
}

// ---------------- MFMA GEMM: h(bf16) = x @ W, + per-head attention dots ----------------
// Block = 256 threads = 4 waves; wave w owns head w (cols w*64..w*64+63).
// M-tile = 16 nodes/block; n=100000 -> 6250 blocks exactly.
__global__ __launch_bounds__(256) void gemm_mfma_kernel(
    const float* __restrict__ x, const unsigned short* __restrict__ Wt,
    const float* __restrict__ att_src, const float* __restrict__ att_dst,
    unsigned short* __restrict__ h, float* __restrict__ a_src, float* __restrict__ a_dst,
    int n)
{
    __shared__ unsigned short As[16][144];   // 16 rows x 128 k, pad to 144 (16B-aligned rows, 4-way max conflict)
    __shared__ unsigned short Hs[16][272];   // 16 rows x 256 cols, pad to 272

    const int t = threadIdx.x;
    const int w = t >> 6;          // wave == head
    const int l = t & 63;
    const int quad = l >> 4;
    const int c15 = l & 15;
    const int base = blockIdx.x * 16;

    // stage A: 16 rows x 128 floats -> bf16 LDS (coalesced float4 reads)
    {
        const float4* xs = (const float4*)(x + (size_t)base * IN_C);
#pragma unroll
        for (int i = 0; i < 2; ++i) {
            int idx = t + i * 256;            // float4 index 0..511
            float4 v = xs[idx];
            int fi = idx * 4;
            int row = fi >> 7, k = fi & 127;
            ushort4 b;
            b.x = f2bf(v.x); b.y = f2bf(v.y); b.z = f2bf(v.z); b.w = f2bf(v.w);
            *(ushort4*)&As[row][k] = b;
        }
    }

    // B fragments in registers: B[k=kt*32+quad*8+j][n=col] = Wt[col][k...]
    short8 bfrag[4][4];
#pragma unroll
    for (int kt = 0; kt < 4; ++kt)
#pragma unroll
        for (int nt = 0; nt < 4; ++nt) {
            int col = w * 64 + nt * 16 + c15;
            int k0 = kt * 32 + quad * 8;
            bfrag[kt][nt] = *(const short8*)(Wt + (size_t)col * IN_C + k0);
        }

    __syncthreads();

    floatx4 acc[4] = {};
#pragma unroll
    for (int kt = 0; kt < 4; ++kt) {
        int k0 = kt * 32 + quad * 8;
        short8 afrag = *(const short8*)&As[c15][k0];   // A[m=c15][k0..k0+7]
#pragma unroll
        for (int nt = 0; nt < 4; ++nt)
            acc[nt] = __builtin_amdgcn_mfma_f32_16x16x32_bf16(afrag, bfrag[kt][nt], acc[nt], 0, 0, 0);
    }

    // epilogue: D layout col=lane&15, row=quad*4+reg
    float asum[4] = {0.f, 0.f, 0.f, 0.f}, adsum[4] = {0.f, 0.f, 0.f, 0.f};
#pragma unroll
    for (int nt = 0; nt < 4; ++nt) {
        int col = w * 64 + nt * 16 + c15;
        float aw = att_src[col];
        float dw = att_dst[col];
#pragma unroll
        for (int r = 0; r < 4; ++r) {
            float v = acc[nt][r];
            Hs[quad * 4 + r][col] = f2bf(v);
            asum[r] = fmaf(v, aw, asum[r]);
            adsum[r] = fmaf(v, dw, adsum[r]);
        }
    }
    // reduce attention dots across the 16 lanes of each quad (cols of this head)
#pragma unroll
    for (int r = 0; r < 4; ++r) {
        float vs = asum[r], vd = adsum[r];
#pragma unroll
        for (int m = 1; m < 16; m <<= 1) {
            vs += __shfl_xor(vs, m, 64);
            vd += __shfl_xor(vd, m, 64);
        }
        if (c15 == 0) {
            int node = base + quad * 4 + r;
            a_src[(size_t)node * HEADS + w] = vs;
            a_dst[(size_t)node * HEADS + w] = vd;
        }
    }

    __syncthreads();
    // coalesced h write: 16x256 bf16 tile
#pragma unroll
    for (int i = 0; i < 2; ++i) {
        int chunk = t + i * 256;        // 0..511, 8 shorts (16B) each
        int si = chunk * 8;
        int row = si >> 8, c0 = si & 255;
        int4 v = *(const int4*)&Hs[row][c0];
        *(int4*)(h + (size_t)(base + row) * OUT_F + c0) = v;
    }
}

// ---------------- CSR build ----------------
__global__ void deg_kernel(const int* __restrict__ ei, int* __restrict__ deg, int E)
{
    int e = blockIdx.x * blockDim.x + threadIdx.x;
    if (e < E) atomicAdd(&deg[ei[E + e]], 1);
}

__global__ void offsets_kernel(const int* __restrict__ deg, int* __restrict__ offsets,
                               int* __restrict__ cursor, int* __restrict__ gcursor, int n)
{
    int i = blockIdx.x * blockDim.x + threadIdx.x;
    int lane = threadIdx.x & 63;
    int cnt = (i < n) ? deg[i] : 0;
    int incl = cnt;
#pragma unroll
    for (int o = 1; o < 64; o <<= 1) {
        int v = __shfl_up(incl, o, 64);
        if (lane >= o) incl += v;
    }
    int total = __shfl(incl, 63, 64);
    int base = 0;
    if (lane == 63) base = atomicAdd(gcursor, total);
    base = __shfl(base, 63, 64);
    int off = base + incl - cnt;
    if (i < n) { offsets[i] = off; cursor[i] = off; }
}

__global__ void scatter_kernel(const int* __restrict__ ei, int* __restrict__ cursor,
                               int* __restrict__ srcs, int E)
{
    int e = blockIdx.x * blockDim.x + threadIdx.x;
    if (e < E) {
        int dst = ei[E + e];
        int pos = atomicAdd(&cursor[dst], 1);
        srcs[pos] = ei[e];
    }
}

// ---------------- Aggregation: one wave per destination node, h in bf16 ----------------
__device__ __forceinline__ float pick_head(float4 v, int h) {
    float lo = (h == 0) ? v.x : v.y;
    float hi = (h == 2) ? v.z : v.w;
    return (h < 2) ? lo : hi;
}

__global__ __launch_bounds__(256) void agg_kernel(
    const unsigned short* __restrict__ h, const float* __restrict__ a_src,
    const float* __restrict__ a_dst, const int* __restrict__ offsets,
    const int* __restrict__ deg, const int* __restrict__ srcs,
    const float* __restrict__ bias, float* __restrict__ out, int n)
{
    int wave = (blockIdx.x * blockDim.x + threadIdx.x) >> 6;
    int lane = threadIdx.x & 63;
    int dst = wave;
    if (dst >= n) return;
    int myh = lane >> 4;   // ushort4 index `lane` covers channels lane*4..lane*4+3, all in head lane>>4

    float4 ad4 = ((const float4*)a_dst)[dst];
    float adh = pick_head(ad4, myh);

    // self loop
    float4 as4 = ((const float4*)a_src)[dst];
    float es = pick_head(as4, myh) + adh;
    es = (es > 0.f) ? es : NEG_SLOPE * es;
    float wgt = __expf(es);
    ushort4 hv = ((const ushort4*)(h + (size_t)dst * OUT_F))[lane];
    float4 acc;
    acc.x = bf2f(hv.x) * wgt; acc.y = bf2f(hv.y) * wgt;
    acc.z = bf2f(hv.z) * wgt; acc.w = bf2f(hv.w) * wgt;
    float wsum = wgt;

    int start = offsets[dst];
    int cnt = deg[dst];
    for (int j = 0; j < cnt; ++j) {
        int s = srcs[start + j];
        float4 as = ((const float4*)a_src)[s];
        float e = pick_head(as, myh) + adh;
        e = (e > 0.f) ? e : NEG_SLOPE * e;
        float we = __expf(e);
        ushort4 hs = ((const ushort4*)(h + (size_t)s * OUT_F))[lane];
        acc.x = fmaf(bf2f(hs.x), we, acc.x);
        acc.y = fmaf(bf2f(hs.y), we, acc.y);
        acc.z = fmaf(bf2f(hs.z), we, acc.z);
        acc.w = fmaf(bf2f(hs.w), we, acc.w);
        wsum += we;
    }

    float inv = 1.f / (wsum + 1e-16f);
    float4 b4 = ((const float4*)bias)[lane];
    float4 o4;
    o4.x = fmaf(acc.x, inv, b4.x);
    o4.y = fmaf(acc.y, inv, b4.y);
    o4.z = fmaf(acc.z, inv, b4.z);
    o4.w = fmaf(acc.w, inv, b4.w);
    ((float4*)(out + (size_t)dst * OUT_F))[lane] = o4;
}

// ---------------- BatchNorm stats (two-level) + apply + ELU ----------------
__global__ __launch_bounds__(256) void stats_partial_kernel(const float* __restrict__ out,
                                                            float* __restrict__ partial, int n)
{
    int c = threadIdx.x;
    int b = blockIdx.x;
    float s = 0.f, s2 = 0.f;
    for (int r = b; r < n; r += SP_BLOCKS) {
        float v = out[(size_t)r * OUT_F + c];
        s += v;
        s2 = fmaf(v, v, s2);
    }
    partial[(size_t)c * SP_BLOCKS + b] = s;
    partial[(size_t)(c + OUT_F) * SP_BLOCKS + b] = s2;
}

__global__ void stats_reduce_kernel(const float* __restrict__ partial, float* __restrict__ stats)
{
    int c = blockIdx.x;    // 0..511
    int l = threadIdx.x;   // 0..63
    float s = 0.f;
    for (int j = l; j < SP_BLOCKS; j += 64) s += partial[(size_t)c * SP_BLOCKS + j];
#pragma unroll
    for (int m = 32; m > 0; m >>= 1) s += __shfl_down(s, m, 64);
    if (l == 0) stats[c] = s;
}

__global__ void scaleshift_kernel(const float* __restrict__ stats,
                                  const float* __restrict__ gamma,
                                  const float* __restrict__ beta,
                                  float* __restrict__ ss, int n)
{
    int c = threadIdx.x;
    float invn = 1.f / (float)n;
    float mean = stats[c] * invn;
    float var = stats[OUT_F + c] * invn - mean * mean;
    float sc = gamma[c] * rsqrtf(var + BN_EPS);
    ss[c] = sc;
    ss[OUT_F + c] = beta[c] - mean * sc;
}

__device__ __forceinline__ float elu1(float v) {
    return (v > 0.f) ? v : expm1f(v);
}

__global__ __launch_bounds__(256) void bn_elu_kernel(float* __restrict__ out,
                                                     const float* __restrict__ ss,
                                                     long long n4)
{
    long long idx = (long long)blockIdx.x * blockDim.x + threadIdx.x;
    if (idx >= n4) return;
    int col4 = (int)(idx & 63);
    float4 v = ((float4*)out)[idx];
    float4 sc = ((const float4*)ss)[col4];
    float4 sh = ((const float4*)(ss + OUT_F))[col4];
    v.x = elu1(fmaf(v.x, sc.x, sh.x));
    v.y = elu1(fmaf(v.y, sc.y, sh.y));
    v.z = elu1(fmaf(v.z, sc.z, sh.z));
    v.w = elu1(fmaf(v.w, sc.w, sh.w));
    ((float4*)out)[idx] = v;
}

// ---------------- launch ----------------
extern "C" void kernel_launch(void* const* d_in, const int* in_sizes, int n_in,
                              void* d_out, int out_size, void* d_ws, size_t ws_size,
                              hipStream_t stream)
{
    const float* x       = (const float*)d_in[0];
    const int*   ei      = (const int*)d_in[1];
    const float* W       = (const float*)d_in[2];
    const float* att_src = (const float*)d_in[3];
    const float* att_dst = (const float*)d_in[4];
    const float* bias    = (const float*)d_in[5];
    const float* gamma   = (const float*)d_in[6];
    const float* beta    = (const float*)d_in[7];
    float* out = (float*)d_out;

    const int n = in_sizes[0] / IN_C;      // 100000
    const int E = in_sizes[1] / 2;         // 1600000

    // ws layout (4-byte units)
    float* ws = (float*)d_ws;
    size_t o = 0;
    unsigned short* h  = (unsigned short*)(ws + o); o += (size_t)n * OUT_F / 2;  // bf16
    unsigned short* Wt = (unsigned short*)(ws + o); o += IN_C * OUT_F / 2;       // bf16
    float* a_src  = ws + o; o += (size_t)n * HEADS;
    float* a_dst  = ws + o; o += (size_t)n * HEADS;
    float* ss     = ws + o; o += 2 * OUT_F;
    float* stats  = ws + o; o += 2 * OUT_F;
    float* partial = ws + o; o += (size_t)2 * OUT_F * SP_BLOCKS;
    int* offsets  = (int*)(ws + o); o += n;
    int* cursor   = (int*)(ws + o); o += n;
    int* srcs     = (int*)(ws + o); o += E;
    // zero-initialized region (contiguous): deg, gcursor
    int* deg      = (int*)(ws + o); o += n;
    int* gcursor  = (int*)(ws + o); o += 1;

    hipMemsetAsync(deg, 0, ((size_t)n + 1) * sizeof(int), stream);

    wtprep_kernel<<<(IN_C * OUT_F) / 256, 256, 0, stream>>>(W, Wt);
    gemm_mfma_kernel<<<(n + 15) / 16, 256, 0, stream>>>(x, Wt, att_src, att_dst, h, a_src, a_dst, n);
    deg_kernel<<<(E + 255) / 256, 256, 0, stream>>>(ei, deg, E);
    offsets_kernel<<<(n + 255) / 256, 256, 0, stream>>>(deg, offsets, cursor, gcursor, n);
    scatter_kernel<<<(E + 255) / 256, 256, 0, stream>>>(ei, cursor, srcs, E);
    agg_kernel<<<(n + 3) / 4, 256, 0, stream>>>(h, a_src, a_dst, offsets, deg, srcs, bias, out, n);
    stats_partial_kernel<<<SP_BLOCKS, 256, 0, stream>>>(out, partial, n);
    stats_reduce_kernel<<<2 * OUT_F, 64, 0, stream>>>(partial, stats);
    scaleshift_kernel<<<1, 256, 0, stream>>>(stats, gamma, beta, ss, n);
    bn_elu_kernel<<<(int)(((long long)n * 64 + 255) / 256), 256, 0, stream>>>(out, ss, (long long)n * 64);
}

// Round 3
// 615.570 us; speedup vs baseline: 1.4734x; 1.1133x over previous
//
#include <hip/hip_runtime.h>

#define IN_C 128
#define HEADS 4
#define OUT_C 64
#define OUT_F 256   // HEADS*OUT_C
#define NEG_SLOPE 0.2f
#define BN_EPS 1e-5f
#define SP_BLOCKS 1024

typedef __attribute__((ext_vector_type(8))) short short8;
typedef __attribute__((ext_vector_type(4))) float floatx4;

__device__ __forceinline__ unsigned short f2bf(float f) {
    unsigned u = __float_as_uint(f);
    u += 0x7FFF + ((u >> 16) & 1);   // round-to-nearest-even
    return (unsigned short)(u >> 16);
}
__device__ __forceinline__ float bf2f(unsigned short u) {
    return __uint_as_float(((unsigned)u) << 16);
}

// ---------------- Wt prep: Wt[col][k] = bf16(W[k][col]) ----------------
__global__ void wtprep_kernel(const float* __restrict__ W, unsigned short* __restrict__ Wt)
{
    int i = blockIdx.x * blockDim.x + threadIdx.x;   // 0..32767
    int c = i >> 7, k = i & 127;
    Wt[i] = f2bf(W[(size_t)k * OUT_F + c]);
}

// ---------------- MFMA GEMM: h(bf16) = x @ W, + per-head attention dots ----------------
__global__ __launch_bounds__(256) void gemm_mfma_kernel(
    const float* __restrict__ x, const unsigned short* __restrict__ Wt,
    const float* __restrict__ att_src, const float* __restrict__ att_dst,
    unsigned short* __restrict__ h, float* __restrict__ a_src, float* __restrict__ a_dst,
    int n)
{
    __shared__ unsigned short As[16][144];
    __shared__ unsigned short Hs[16][272];

    const int t = threadIdx.x;
    const int w = t >> 6;          // wave == head
    const int l = t & 63;
    const int quad = l >> 4;
    const int c15 = l & 15;
    const int base = blockIdx.x * 16;

    {
        const float4* xs = (const float4*)(x + (size_t)base * IN_C);
#pragma unroll
        for (int i = 0; i < 2; ++i) {
            int idx = t + i * 256;
            float4 v = xs[idx];
            int fi = idx * 4;
            int row = fi >> 7, k = fi & 127;
            ushort4 b;
            b.x = f2bf(v.x); b.y = f2bf(v.y); b.z = f2bf(v.z); b.w = f2bf(v.w);
            *(ushort4*)&As[row][k] = b;
        }
    }

    short8 bfrag[4][4];
#pragma unroll
    for (int kt = 0; kt < 4; ++kt)
#pragma unroll
        for (int nt = 0; nt < 4; ++nt) {
            int col = w * 64 + nt * 16 + c15;
            int k0 = kt * 32 + quad * 8;
            bfrag[kt][nt] = *(const short8*)(Wt + (size_t)col * IN_C + k0);
        }

    __syncthreads();

    floatx4 acc[4] = {};
#pragma unroll
    for (int kt = 0; kt < 4; ++kt) {
        int k0 = kt * 32 + quad * 8;
        short8 afrag = *(const short8*)&As[c15][k0];
#pragma unroll
        for (int nt = 0; nt < 4; ++nt)
            acc[nt] = __builtin_amdgcn_mfma_f32_16x16x32_bf16(afrag, bfrag[kt][nt], acc[nt], 0, 0, 0);
    }

    float asum[4] = {0.f, 0.f, 0.f, 0.f}, adsum[4] = {0.f, 0.f, 0.f, 0.f};
#pragma unroll
    for (int nt = 0; nt < 4; ++nt) {
        int col = w * 64 + nt * 16 + c15;
        float aw = att_src[col];
        float dw = att_dst[col];
#pragma unroll
        for (int r = 0; r < 4; ++r) {
            float v = acc[nt][r];
            Hs[quad * 4 + r][col] = f2bf(v);
            asum[r] = fmaf(v, aw, asum[r]);
            adsum[r] = fmaf(v, dw, adsum[r]);
        }
    }
#pragma unroll
    for (int r = 0; r < 4; ++r) {
        float vs = asum[r], vd = adsum[r];
#pragma unroll
        for (int m = 1; m < 16; m <<= 1) {
            vs += __shfl_xor(vs, m, 64);
            vd += __shfl_xor(vd, m, 64);
        }
        if (c15 == 0) {
            int node = base + quad * 4 + r;
            a_src[(size_t)node * HEADS + w] = vs;
            a_dst[(size_t)node * HEADS + w] = vd;
        }
    }

    __syncthreads();
#pragma unroll
    for (int i = 0; i < 2; ++i) {
        int chunk = t + i * 256;
        int si = chunk * 8;
        int row = si >> 8, c0 = si & 255;
        int4 v = *(const int4*)&Hs[row][c0];
        *(int4*)(h + (size_t)(base + row) * OUT_F + c0) = v;
    }
}

// ---------------- CSR build ----------------
__global__ void deg_kernel(const int* __restrict__ ei, int* __restrict__ deg, int E)
{
    int e = blockIdx.x * blockDim.x + threadIdx.x;
    if (e < E) atomicAdd(&deg[ei[E + e]], 1);
}

__global__ void offsets_kernel(const int* __restrict__ deg, int* __restrict__ offsets,
                               int* __restrict__ cursor, int* __restrict__ gcursor, int n)
{
    int i = blockIdx.x * blockDim.x + threadIdx.x;
    int lane = threadIdx.x & 63;
    int cnt = (i < n) ? deg[i] : 0;
    int incl = cnt;
#pragma unroll
    for (int o = 1; o < 64; o <<= 1) {
        int v = __shfl_up(incl, o, 64);
        if (lane >= o) incl += v;
    }
    int total = __shfl(incl, 63, 64);
    int base = 0;
    if (lane == 63) base = atomicAdd(gcursor, total);
    base = __shfl(base, 63, 64);
    int off = base + incl - cnt;
    if (i < n) { offsets[i] = off; cursor[i] = off; }
}

__global__ void scatter_kernel(const int* __restrict__ ei, int* __restrict__ cursor,
                               int* __restrict__ srcs, int E)
{
    int e = blockIdx.x * blockDim.x + threadIdx.x;
    if (e < E) {
        int dst = ei[E + e];
        int pos = atomicAdd(&cursor[dst], 1);
        srcs[pos] = ei[e];
    }
}

// ---------------- Aggregation: one wave per destination node, 4x-unrolled edge loop ----------------
__global__ __launch_bounds__(256) void agg_kernel(
    const unsigned short* __restrict__ h, const float* __restrict__ a_src,
    const float* __restrict__ a_dst, const int* __restrict__ offsets,
    const int* __restrict__ deg, const int* __restrict__ srcs,
    const float* __restrict__ bias, float* __restrict__ out, int n)
{
    int wave = (blockIdx.x * blockDim.x + threadIdx.x) >> 6;
    int lane = threadIdx.x & 63;
    int dst = wave;
    if (dst >= n) return;
    int myh = lane >> 4;

    float adh = a_dst[(size_t)dst * HEADS + myh];

    // self loop
    float es = a_src[(size_t)dst * HEADS + myh] + adh;
    es = (es > 0.f) ? es : NEG_SLOPE * es;
    float wgt = __expf(es);
    ushort4 hv = ((const ushort4*)(h + (size_t)dst * OUT_F))[lane];
    float4 acc;
    acc.x = bf2f(hv.x) * wgt; acc.y = bf2f(hv.y) * wgt;
    acc.z = bf2f(hv.z) * wgt; acc.w = bf2f(hv.w) * wgt;
    float wsum = wgt;

    const int start = offsets[dst];
    const int cnt = deg[dst];
    int j = 0;
    for (; j + 4 <= cnt; j += 4) {
        // batch of 4 independent edges: issue all index loads, then all gathers
        int s0 = srcs[start + j + 0];
        int s1 = srcs[start + j + 1];
        int s2 = srcs[start + j + 2];
        int s3 = srcs[start + j + 3];
        float e0 = a_src[(size_t)s0 * HEADS + myh];
        float e1 = a_src[(size_t)s1 * HEADS + myh];
        float e2 = a_src[(size_t)s2 * HEADS + myh];
        float e3 = a_src[(size_t)s3 * HEADS + myh];
        ushort4 h0 = ((const ushort4*)(h + (size_t)s0 * OUT_F))[lane];
        ushort4 h1 = ((const ushort4*)(h + (size_t)s1 * OUT_F))[lane];
        ushort4 h2 = ((const ushort4*)(h + (size_t)s2 * OUT_F))[lane];
        ushort4 h3 = ((const ushort4*)(h + (size_t)s3 * OUT_F))[lane];
        e0 += adh; e0 = (e0 > 0.f) ? e0 : NEG_SLOPE * e0; float w0 = __expf(e0);
        e1 += adh; e1 = (e1 > 0.f) ? e1 : NEG_SLOPE * e1; float w1 = __expf(e1);
        e2 += adh; e2 = (e2 > 0.f) ? e2 : NEG_SLOPE * e2; float w2 = __expf(e2);
        e3 += adh; e3 = (e3 > 0.f) ? e3 : NEG_SLOPE * e3; float w3 = __expf(e3);
        acc.x = fmaf(bf2f(h0.x), w0, acc.x);
        acc.y = fmaf(bf2f(h0.y), w0, acc.y);
        acc.z = fmaf(bf2f(h0.z), w0, acc.z);
        acc.w = fmaf(bf2f(h0.w), w0, acc.w);
        acc.x = fmaf(bf2f(h1.x), w1, acc.x);
        acc.y = fmaf(bf2f(h1.y), w1, acc.y);
        acc.z = fmaf(bf2f(h1.z), w1, acc.z);
        acc.w = fmaf(bf2f(h1.w), w1, acc.w);
        acc.x = fmaf(bf2f(h2.x), w2, acc.x);
        acc.y = fmaf(bf2f(h2.y), w2, acc.y);
        acc.z = fmaf(bf2f(h2.z), w2, acc.z);
        acc.w = fmaf(bf2f(h2.w), w2, acc.w);
        acc.x = fmaf(bf2f(h3.x), w3, acc.x);
        acc.y = fmaf(bf2f(h3.y), w3, acc.y);
        acc.z = fmaf(bf2f(h3.z), w3, acc.z);
        acc.w = fmaf(bf2f(h3.w), w3, acc.w);
        wsum += w0 + w1 + w2 + w3;
    }
    for (; j < cnt; ++j) {
        int s = srcs[start + j];
        float e = a_src[(size_t)s * HEADS + myh] + adh;
        e = (e > 0.f) ? e : NEG_SLOPE * e;
        float we = __expf(e);
        ushort4 hs = ((const ushort4*)(h + (size_t)s * OUT_F))[lane];
        acc.x = fmaf(bf2f(hs.x), we, acc.x);
        acc.y = fmaf(bf2f(hs.y), we, acc.y);
        acc.z = fmaf(bf2f(hs.z), we, acc.z);
        acc.w = fmaf(bf2f(hs.w), we, acc.w);
        wsum += we;
    }

    float inv = 1.f / (wsum + 1e-16f);
    float4 b4 = ((const float4*)bias)[lane];
    float4 o4;
    o4.x = fmaf(acc.x, inv, b4.x);
    o4.y = fmaf(acc.y, inv, b4.y);
    o4.z = fmaf(acc.z, inv, b4.z);
    o4.w = fmaf(acc.w, inv, b4.w);
    ((float4*)(out + (size_t)dst * OUT_F))[lane] = o4;
}

// ---------------- BatchNorm stats (two-level) + apply + ELU ----------------
__global__ __launch_bounds__(256) void stats_partial_kernel(const float* __restrict__ out,
                                                            float* __restrict__ partial, int n)
{
    int c = threadIdx.x;
    int b = blockIdx.x;
    float s = 0.f, s2 = 0.f;
    for (int r = b; r < n; r += SP_BLOCKS) {
        float v = out[(size_t)r * OUT_F + c];
        s += v;
        s2 = fmaf(v, v, s2);
    }
    partial[(size_t)c * SP_BLOCKS + b] = s;
    partial[(size_t)(c + OUT_F) * SP_BLOCKS + b] = s2;
}

__global__ void stats_reduce_kernel(const float* __restrict__ partial, float* __restrict__ stats)
{
    int c = blockIdx.x;    // 0..511
    int l = threadIdx.x;   // 0..63
    float s = 0.f;
    for (int j = l; j < SP_BLOCKS; j += 64) s += partial[(size_t)c * SP_BLOCKS + j];
#pragma unroll
    for (int m = 32; m > 0; m >>= 1) s += __shfl_down(s, m, 64);
    if (l == 0) stats[c] = s;
}

__global__ void scaleshift_kernel(const float* __restrict__ stats,
                                  const float* __restrict__ gamma,
                                  const float* __restrict__ beta,
                                  float* __restrict__ ss, int n)
{
    int c = threadIdx.x;
    float invn = 1.f / (float)n;
    float mean = stats[c] * invn;
    float var = stats[OUT_F + c] * invn - mean * mean;
    float sc = gamma[c] * rsqrtf(var + BN_EPS);
    ss[c] = sc;
    ss[OUT_F + c] = beta[c] - mean * sc;
}

__device__ __forceinline__ float elu1(float v) {
    return (v > 0.f) ? v : expm1f(v);
}

__global__ __launch_bounds__(256) void bn_elu_kernel(float* __restrict__ out,
                                                     const float* __restrict__ ss,
                                                     long long n4)
{
    long long idx = (long long)blockIdx.x * blockDim.x + threadIdx.x;
    if (idx >= n4) return;
    int col4 = (int)(idx & 63);
    float4 v = ((float4*)out)[idx];
    float4 sc = ((const float4*)ss)[col4];
    float4 sh = ((const float4*)(ss + OUT_F))[col4];
    v.x = elu1(fmaf(v.x, sc.x, sh.x));
    v.y = elu1(fmaf(v.y, sc.y, sh.y));
    v.z = elu1(fmaf(v.z, sc.z, sh.z));
    v.w = elu1(fmaf(v.w, sc.w, sh.w));
    ((float4*)out)[idx] = v;
}

// ---------------- launch ----------------
extern "C" void kernel_launch(void* const* d_in, const int* in_sizes, int n_in,
                              void* d_out, int out_size, void* d_ws, size_t ws_size,
                              hipStream_t stream)
{
    const float* x       = (const float*)d_in[0];
    const int*   ei      = (const int*)d_in[1];
    const float* W       = (const float*)d_in[2];
    const float* att_src = (const float*)d_in[3];
    const float* att_dst = (const float*)d_in[4];
    const float* bias    = (const float*)d_in[5];
    const float* gamma   = (const float*)d_in[6];
    const float* beta    = (const float*)d_in[7];
    float* out = (float*)d_out;

    const int n = in_sizes[0] / IN_C;      // 100000
    const int E = in_sizes[1] / 2;         // 1600000

    float* ws = (float*)d_ws;
    size_t o = 0;
    unsigned short* h  = (unsigned short*)(ws + o); o += (size_t)n * OUT_F / 2;  // bf16
    unsigned short* Wt = (unsigned short*)(ws + o); o += IN_C * OUT_F / 2;       // bf16
    float* a_src  = ws + o; o += (size_t)n * HEADS;
    float* a_dst  = ws + o; o += (size_t)n * HEADS;
    float* ss     = ws + o; o += 2 * OUT_F;
    float* stats  = ws + o; o += 2 * OUT_F;
    float* partial = ws + o; o += (size_t)2 * OUT_F * SP_BLOCKS;
    int* offsets  = (int*)(ws + o); o += n;
    int* cursor   = (int*)(ws + o); o += n;
    int* srcs     = (int*)(ws + o); o += E;
    int* deg      = (int*)(ws + o); o += n;
    int* gcursor  = (int*)(ws + o); o += 1;

    hipMemsetAsync(deg, 0, ((size_t)n + 1) * sizeof(int), stream);

    wtprep_kernel<<<(IN_C * OUT_F) / 256, 256, 0, stream>>>(W, Wt);
    gemm_mfma_kernel<<<(n + 15) / 16, 256, 0, stream>>>(x, Wt, att_src, att_dst, h, a_src, a_dst, n);
    deg_kernel<<<(E + 255) / 256, 256, 0, stream>>>(ei, deg, E);
    offsets_kernel<<<(n + 255) / 256, 256, 0, stream>>>(deg, offsets, cursor, gcursor, n);
    scatter_kernel<<<(E + 255) / 256, 256, 0, stream>>>(ei, cursor, srcs, E);
    agg_kernel<<<(n + 3) / 4, 256, 0, stream>>>(h, a_src, a_dst, offsets, deg, srcs, bias, out, n);
    stats_partial_kernel<<<SP_BLOCKS, 256, 0, stream>>>(out, partial, n);
    stats_reduce_kernel<<<2 * OUT_F, 64, 0, stream>>>(partial, stats);
    scaleshift_kernel<<<1, 256, 0, stream>>>(stats, gamma, beta, ss, n);
    bn_elu_kernel<<<(int)(((long long)n * 64 + 255) / 256), 256, 0, stream>>>(out, ss, (long long)n * 64);
}

// Round 4
// 575.505 us; speedup vs baseline: 1.5760x; 1.0696x over previous
//
#include <hip/hip_runtime.h>

#define IN_C 128
#define HEADS 4
#define OUT_C 64
#define OUT_F 256   // HEADS*OUT_C
#define NEG_SLOPE 0.2f
#define BN_EPS 1e-5f
#define NBUCK 64

typedef __attribute__((ext_vector_type(8))) short short8;
typedef __attribute__((ext_vector_type(4))) float floatx4;

__device__ __forceinline__ unsigned short f2bf(float f) {
    unsigned u = __float_as_uint(f);
    u += 0x7FFF + ((u >> 16) & 1);   // round-to-nearest-even
    return (unsigned short)(u >> 16);
}
__device__ __forceinline__ float bf2f(unsigned short u) {
    return __uint_as_float(((unsigned)u) << 16);
}

// ---------------- Wp prep: fragment-ordered bf16 weights ----------------
// Wp[((w*4+kt)*4+nt)*512 + l*8 + j] = bf16( W[(kt*32+(l>>4)*8+j) * OUT_F + (w*64+nt*16+(l&15))] )
// so gemm's bfrag load is lane-consecutive 16B -> one coalesced 1KB transaction.
__global__ void wtprep_kernel(const float* __restrict__ W, unsigned short* __restrict__ Wp)
{
    int idx = blockIdx.x * blockDim.x + threadIdx.x;   // 0..32767
    int j  = idx & 7;
    int l  = (idx >> 3) & 63;
    int nt = (idx >> 9) & 3;
    int kt = (idx >> 11) & 3;
    int w  = idx >> 13;
    int k   = kt * 32 + (l >> 4) * 8 + j;
    int col = w * 64 + nt * 16 + (l & 15);
    Wp[idx] = f2bf(W[(size_t)k * OUT_F + col]);
}

// ---------------- MFMA GEMM: h(bf16) = x @ W, + per-head attention dots ----------------
__global__ __launch_bounds__(256) void gemm_mfma_kernel(
    const float* __restrict__ x, const unsigned short* __restrict__ Wp,
    const float* __restrict__ att_src, const float* __restrict__ att_dst,
    unsigned short* __restrict__ h, float* __restrict__ a_src, float* __restrict__ a_dst,
    int n)
{
    __shared__ unsigned short As[16][144];
    __shared__ unsigned short Hs[16][268];   // row stride 268 shorts: quads land on disjoint bank groups

    const int t = threadIdx.x;
    const int w = t >> 6;          // wave == head
    const int l = t & 63;
    const int quad = l >> 4;
    const int c15 = l & 15;
    const int base = blockIdx.x * 16;

    {
        const float4* xs = (const float4*)(x + (size_t)base * IN_C);
#pragma unroll
        for (int i = 0; i < 2; ++i) {
            int idx = t + i * 256;
            float4 v = xs[idx];
            int fi = idx * 4;
            int row = fi >> 7, k = fi & 127;
            ushort4 b;
            b.x = f2bf(v.x); b.y = f2bf(v.y); b.z = f2bf(v.z); b.w = f2bf(v.w);
            *(ushort4*)&As[row][k] = b;
        }
    }

    // coalesced fragment loads (1KB per wave instruction)
    short8 bfrag[4][4];
#pragma unroll
    for (int kt = 0; kt < 4; ++kt)
#pragma unroll
        for (int nt = 0; nt < 4; ++nt)
            bfrag[kt][nt] = *(const short8*)(Wp + (((w * 4 + kt) * 4 + nt) << 9) + l * 8);

    __syncthreads();

    floatx4 acc[4] = {};
#pragma unroll
    for (int kt = 0; kt < 4; ++kt) {
        int k0 = kt * 32 + quad * 8;
        short8 afrag = *(const short8*)&As[c15][k0];
#pragma unroll
        for (int nt = 0; nt < 4; ++nt)
            acc[nt] = __builtin_amdgcn_mfma_f32_16x16x32_bf16(afrag, bfrag[kt][nt], acc[nt], 0, 0, 0);
    }

    float asum[4] = {0.f, 0.f, 0.f, 0.f}, adsum[4] = {0.f, 0.f, 0.f, 0.f};
#pragma unroll
    for (int nt = 0; nt < 4; ++nt) {
        int col = w * 64 + nt * 16 + c15;
        float aw = att_src[col];
        float dw = att_dst[col];
#pragma unroll
        for (int r = 0; r < 4; ++r) {
            float v = acc[nt][r];
            Hs[quad * 4 + r][col] = f2bf(v);
            asum[r] = fmaf(v, aw, asum[r]);
            adsum[r] = fmaf(v, dw, adsum[r]);
        }
    }
#pragma unroll
    for (int r = 0; r < 4; ++r) {
        float vs = asum[r], vd = adsum[r];
#pragma unroll
        for (int m = 1; m < 16; m <<= 1) {
            vs += __shfl_xor(vs, m, 64);
            vd += __shfl_xor(vd, m, 64);
        }
        if (c15 == 0) {
            int node = base + quad * 4 + r;
            a_src[(size_t)node * HEADS + w] = vs;
            a_dst[(size_t)node * HEADS + w] = vd;
        }
    }

    __syncthreads();
#pragma unroll
    for (int i = 0; i < 2; ++i) {
        int chunk = t + i * 256;
        int si = chunk * 8;
        int row = si >> 8, c0 = si & 255;
        int4 v = *(const int4*)&Hs[row][c0];
        *(int4*)(h + (size_t)(base + row) * OUT_F + c0) = v;
    }
}

// ---------------- CSR build ----------------
__global__ void deg_kernel(const int* __restrict__ ei, int* __restrict__ deg, int E)
{
    int e = blockIdx.x * blockDim.x + threadIdx.x;
    if (e < E) atomicAdd(&deg[ei[E + e]], 1);
}

__global__ void offsets_kernel(const int* __restrict__ deg, int* __restrict__ offsets,
                               int* __restrict__ cursor, int* __restrict__ gcursor, int n)
{
    int i = blockIdx.x * blockDim.x + threadIdx.x;
    int lane = threadIdx.x & 63;
    int cnt = (i < n) ? deg[i] : 0;
    int incl = cnt;
#pragma unroll
    for (int o = 1; o < 64; o <<= 1) {
        int v = __shfl_up(incl, o, 64);
        if (lane >= o) incl += v;
    }
    int total = __shfl(incl, 63, 64);
    int base = 0;
    if (lane == 63) base = atomicAdd(gcursor, total);
    base = __shfl(base, 63, 64);
    int off = base + incl - cnt;
    if (i < n) { offsets[i] = off; cursor[i] = off; }
}

__global__ void scatter_kernel(const int* __restrict__ ei, int* __restrict__ cursor,
                               int* __restrict__ srcs, int E)
{
    int e = blockIdx.x * blockDim.x + threadIdx.x;
    if (e < E) {
        int dst = ei[E + e];
        int pos = atomicAdd(&cursor[dst], 1);
        srcs[pos] = ei[e];
    }
}

// ---------------- Aggregation: one wave per dst, 8x-unrolled, fused BN stats ----------------
__global__ __launch_bounds__(256) void agg_kernel(
    const unsigned short* __restrict__ h, const float* __restrict__ a_src,
    const float* __restrict__ a_dst, const int* __restrict__ offsets,
    const int* __restrict__ deg, const int* __restrict__ srcs,
    const float* __restrict__ bias, float* __restrict__ out,
    float* __restrict__ sbuck, int n)
{
    __shared__ float red[2][4][OUT_F];   // 8KB: [s|s2][wave][col]

    int wave_in_blk = threadIdx.x >> 6;
    int lane = threadIdx.x & 63;
    int dst = blockIdx.x * 4 + wave_in_blk;
    int myh = lane >> 4;
    bool valid = (dst < n);

    float4 o4 = {0.f, 0.f, 0.f, 0.f};

    if (valid) {
        float adh = a_dst[(size_t)dst * HEADS + myh];

        // self loop
        float es = a_src[(size_t)dst * HEADS + myh] + adh;
        es = (es > 0.f) ? es : NEG_SLOPE * es;
        float wgt = __expf(es);
        ushort4 hv = ((const ushort4*)(h + (size_t)dst * OUT_F))[lane];
        float4 acc;
        acc.x = bf2f(hv.x) * wgt; acc.y = bf2f(hv.y) * wgt;
        acc.z = bf2f(hv.z) * wgt; acc.w = bf2f(hv.w) * wgt;
        float wsum = wgt;

        const int start = offsets[dst];
        const int cnt = deg[dst];
        int j = 0;
        for (; j + 8 <= cnt; j += 8) {
            int s[8];
#pragma unroll
            for (int u = 0; u < 8; ++u) s[u] = srcs[start + j + u];
            float ew[8];
#pragma unroll
            for (int u = 0; u < 8; ++u) ew[u] = a_src[(size_t)s[u] * HEADS + myh];
            ushort4 hh[8];
#pragma unroll
            for (int u = 0; u < 8; ++u) hh[u] = ((const ushort4*)(h + (size_t)s[u] * OUT_F))[lane];
#pragma unroll
            for (int u = 0; u < 8; ++u) {
                float e = ew[u] + adh;
                e = (e > 0.f) ? e : NEG_SLOPE * e;
                float wv = __expf(e);
                acc.x = fmaf(bf2f(hh[u].x), wv, acc.x);
                acc.y = fmaf(bf2f(hh[u].y), wv, acc.y);
                acc.z = fmaf(bf2f(hh[u].z), wv, acc.z);
                acc.w = fmaf(bf2f(hh[u].w), wv, acc.w);
                wsum += wv;
            }
        }
        for (; j < cnt; ++j) {
            int s = srcs[start + j];
            float e = a_src[(size_t)s * HEADS + myh] + adh;
            e = (e > 0.f) ? e : NEG_SLOPE * e;
            float we = __expf(e);
            ushort4 hs = ((const ushort4*)(h + (size_t)s * OUT_F))[lane];
            acc.x = fmaf(bf2f(hs.x), we, acc.x);
            acc.y = fmaf(bf2f(hs.y), we, acc.y);
            acc.z = fmaf(bf2f(hs.z), we, acc.z);
            acc.w = fmaf(bf2f(hs.w), we, acc.w);
            wsum += we;
        }

        float inv = 1.f / (wsum + 1e-16f);
        float4 b4 = ((const float4*)bias)[lane];
        o4.x = fmaf(acc.x, inv, b4.x);
        o4.y = fmaf(acc.y, inv, b4.y);
        o4.z = fmaf(acc.z, inv, b4.z);
        o4.w = fmaf(acc.w, inv, b4.w);
        ((float4*)(out + (size_t)dst * OUT_F))[lane] = o4;
    }

    // fused BN-stat accumulation (per-block reduce -> bucketed atomics)
    int c0 = lane * 4;
    *(float4*)&red[0][wave_in_blk][c0] = o4;
    float4 q4;
    q4.x = o4.x * o4.x; q4.y = o4.y * o4.y; q4.z = o4.z * o4.z; q4.w = o4.w * o4.w;
    *(float4*)&red[1][wave_in_blk][c0] = q4;
    __syncthreads();

    int t = threadIdx.x;   // column 0..255
    float s  = red[0][0][t] + red[0][1][t] + red[0][2][t] + red[0][3][t];
    float s2 = red[1][0][t] + red[1][1][t] + red[1][2][t] + red[1][3][t];
    float* bk = sbuck + (size_t)(blockIdx.x & (NBUCK - 1)) * (2 * OUT_F);
    atomicAdd(&bk[t], s);
    atomicAdd(&bk[OUT_F + t], s2);
}

// ---------------- bucket reduce -> scale/shift coefficients ----------------
__global__ void statsfinal_kernel(const float* __restrict__ sbuck,
                                  const float* __restrict__ gamma,
                                  const float* __restrict__ beta,
                                  float* __restrict__ ss, int n)
{
    int c = threadIdx.x;   // 0..255
    float s = 0.f, s2 = 0.f;
    for (int b = 0; b < NBUCK; ++b) {
        s  += sbuck[(size_t)b * (2 * OUT_F) + c];
        s2 += sbuck[(size_t)b * (2 * OUT_F) + OUT_F + c];
    }
    float invn = 1.f / (float)n;
    float mean = s * invn;
    float var = s2 * invn - mean * mean;
    float sc = gamma[c] * rsqrtf(var + BN_EPS);
    ss[c] = sc;
    ss[OUT_F + c] = beta[c] - mean * sc;
}

__device__ __forceinline__ float elu1(float v) {
    return (v > 0.f) ? v : expm1f(v);
}

__global__ __launch_bounds__(256) void bn_elu_kernel(float* __restrict__ out,
                                                     const float* __restrict__ ss,
                                                     long long n4)
{
    long long idx = (long long)blockIdx.x * blockDim.x + threadIdx.x;
    if (idx >= n4) return;
    int col4 = (int)(idx & 63);
    float4 v = ((float4*)out)[idx];
    float4 sc = ((const float4*)ss)[col4];
    float4 sh = ((const float4*)(ss + OUT_F))[col4];
    v.x = elu1(fmaf(v.x, sc.x, sh.x));
    v.y = elu1(fmaf(v.y, sc.y, sh.y));
    v.z = elu1(fmaf(v.z, sc.z, sh.z));
    v.w = elu1(fmaf(v.w, sc.w, sh.w));
    ((float4*)out)[idx] = v;
}

// ---------------- launch ----------------
extern "C" void kernel_launch(void* const* d_in, const int* in_sizes, int n_in,
                              void* d_out, int out_size, void* d_ws, size_t ws_size,
                              hipStream_t stream)
{
    const float* x       = (const float*)d_in[0];
    const int*   ei      = (const int*)d_in[1];
    const float* W       = (const float*)d_in[2];
    const float* att_src = (const float*)d_in[3];
    const float* att_dst = (const float*)d_in[4];
    const float* bias    = (const float*)d_in[5];
    const float* gamma   = (const float*)d_in[6];
    const float* beta    = (const float*)d_in[7];
    float* out = (float*)d_out;

    const int n = in_sizes[0] / IN_C;      // 100000
    const int E = in_sizes[1] / 2;         // 1600000

    float* ws = (float*)d_ws;
    size_t o = 0;
    unsigned short* h  = (unsigned short*)(ws + o); o += (size_t)n * OUT_F / 2;  // bf16
    unsigned short* Wp = (unsigned short*)(ws + o); o += IN_C * OUT_F / 2;       // bf16, frag-packed
    float* a_src  = ws + o; o += (size_t)n * HEADS;
    float* a_dst  = ws + o; o += (size_t)n * HEADS;
    float* ss     = ws + o; o += 2 * OUT_F;
    int* offsets  = (int*)(ws + o); o += n;
    int* cursor   = (int*)(ws + o); o += n;
    int* srcs     = (int*)(ws + o); o += E;
    // zero-initialized region (contiguous): deg, gcursor, sbuck
    int* deg      = (int*)(ws + o); o += n;
    int* gcursor  = (int*)(ws + o); o += 1;
    float* sbuck  = ws + o; o += (size_t)NBUCK * 2 * OUT_F;

    hipMemsetAsync(deg, 0, ((size_t)n + 1 + (size_t)NBUCK * 2 * OUT_F) * sizeof(int), stream);

    wtprep_kernel<<<(IN_C * OUT_F) / 256, 256, 0, stream>>>(W, Wp);
    gemm_mfma_kernel<<<(n + 15) / 16, 256, 0, stream>>>(x, Wp, att_src, att_dst, h, a_src, a_dst, n);
    deg_kernel<<<(E + 255) / 256, 256, 0, stream>>>(ei, deg, E);
    offsets_kernel<<<(n + 255) / 256, 256, 0, stream>>>(deg, offsets, cursor, gcursor, n);
    scatter_kernel<<<(E + 255) / 256, 256, 0, stream>>>(ei, cursor, srcs, E);
    agg_kernel<<<(n + 3) / 4, 256, 0, stream>>>(h, a_src, a_dst, offsets, deg, srcs, bias, out, sbuck, n);
    statsfinal_kernel<<<1, 256, 0, stream>>>(sbuck, gamma, beta, ss, n);
    bn_elu_kernel<<<(int)(((long long)n * 64 + 255) / 256), 256, 0, stream>>>(out, ss, (long long)n * 64);
}